// Round 1
// baseline (1688.524 us; speedup 1.0000x reference)
//
#include <hip/hip_runtime.h>
#include <hip/hip_bf16.h>

// Problem constants (from reference): B=4, T=512, H=2048, V=32000
#define B_ 4
#define T_ 512
#define H_ 2048
#define V_ 32000
#define M_ (B_ * T_)          // 2048 tokens
#define BETA_ 0.1f

// GEMM tiling: 256x256 block tile, BK=64, 512 threads = 8 waves (2M x 4N),
// each wave owns a 128x64 output sub-tile. LDS double-buffered 2 x 64 KB.
#define BM 256
#define BN 256
#define BK 64
#define NKT (H_ / BK)         // 32 k-tiles
#define NTILES (V_ / BN)      // 125 n-tiles
#define NP (NTILES * 4)       // 500 partial slabs (64 cols each) per row
#define NPAD 512              // padded row length for [m][p] partial layout
#define GRID_GEMM 1024        // 8 xcd * 128 g; g>>3 -> nt-group, g&7 -> mb

#define ABYTES (BM * BK * 2)      // 32 KB per A (or B) tile
#define BUFBYTES (2 * ABYTES)     // 64 KB: A tile then B tile
#define LDS_TOTAL (2 * BUFBYTES)  // 128 KB double-buffered

typedef __attribute__((ext_vector_type(8))) short short8;  // 8 bf16 = 4 VGPRs
typedef __attribute__((ext_vector_type(4))) float f32x4;   // MFMA accumulator

__device__ __forceinline__ void async_copy16(const void* g, void* l) {
  // global -> LDS direct copy, 16B per lane. LDS dest must be wave-uniform
  // base + lane*16 (it is: slot index is lane-linear within each wave).
  __builtin_amdgcn_global_load_lds(
      (const __attribute__((address_space(1))) void*)g,
      (__attribute__((address_space(3))) void*)l, 16, 0, 0);
}

__device__ __forceinline__ unsigned short f2bf(float f) {
  unsigned int u = __float_as_uint(f);
  u += 0x7fffu + ((u >> 16) & 1u);
  return (unsigned short)(u >> 16);
}

__global__ void cvt_bf16_kernel(const float* __restrict__ in,
                                unsigned short* __restrict__ out, int n4) {
  int i = blockIdx.x * blockDim.x + threadIdx.x;
  if (i < n4) {
    float4 v = ((const float4*)in)[i];
    ushort4 o;
    o.x = f2bf(v.x); o.y = f2bf(v.y); o.z = f2bf(v.z); o.w = f2bf(v.w);
    ((ushort4*)out)[i] = o;
  }
}

// Selected logit: exact fp32 dot(x[m,:], W[ids[m],:]). One wave per (model, token).
__global__ void sel_kernel(const float* __restrict__ x, const float* __restrict__ w,
                           const float* __restrict__ rx, const float* __restrict__ rw,
                           const int* __restrict__ ids, float* __restrict__ sel) {
  int gw = (blockIdx.x * 256 + threadIdx.x) >> 6;  // global wave id, 0..4095
  int l = threadIdx.x & 63;
  int md = gw >> 11;          // model: 0 = policy, 1 = ref
  int m = gw & (M_ - 1);      // token
  const float* xr = (md ? rx : x) + (size_t)m * H_;
  const float* wr = (md ? rw : w) + (size_t)ids[m] * H_;
  float s = 0.0f;
#pragma unroll
  for (int it = 0; it < H_ / 256; ++it) {
    int k = it * 256 + l * 4;
    float4 a = *(const float4*)(xr + k);
    float4 b = *(const float4*)(wr + k);
    s += a.x * b.x + a.y * b.y + a.z * b.z + a.w * b.w;
  }
#pragma unroll
  for (int off = 32; off; off >>= 1) s += __shfl_xor(s, off, 64);
  if (l == 0) sel[md * M_ + m] = s;
}

// Fused bf16 MFMA GEMM (logits = A * Bw^T) + per-row online (max, sumexp) over
// each wave's 64-column slab.
//
// Pipeline (T3 minimum-2-phase, guide-verified recipe): explicit LDS double
// buffer; each iteration ISSUES the next K-tile's 8 global_load_lds first,
// then computes the current K-tile (24 ds_read_b128 + 64 MFMA per wave), then
// hits the single barrier. The barrier's implicit vmcnt(0) drain thus lands a
// full K-tile of compute (~2048 MFMA-cyc/CU) after load issue, hiding the
// ~900-cyc HBM latency that made the previous BK=32 single-buffer version
// latency-bound (MfmaUtil 19%).
//
// LDS layout per tile: K-outer [kb 0..7][row 0..255][16B] — lane-linear rows
// make both global_load_lds staging and ds_read_b128 fragment reads
// conflict-free (SQ_LDS_BANK_CONFLICT = 0 on the previous kernel with the
// same layout family).
//
// XCD-aware decode: the 8 m-blocks of one n-tile land consecutively on one
// XCD (linear&7) so the 32 KB B k-slice is fetched into that XCD's L2 once.
__global__ __launch_bounds__(512, 2) void gemm_lse_kernel(
    const unsigned short* __restrict__ A,    // [M_][H_] bf16
    const unsigned short* __restrict__ Bw,   // [V_][H_] bf16
    float* __restrict__ pmax,                // [M_][NPAD]
    float* __restrict__ psum) {              // [M_][NPAD]
  const int linear = blockIdx.x;
  const int c = linear & 7, g = linear >> 3;
  const int nt = (g >> 3) * 8 + c;           // n-tile, xcd-grouped
  if (nt >= NTILES) return;
  const int mb = g & 7;                      // m-block

  extern __shared__ char smem[];             // 2 x (A 32KB | B 32KB)

  const int tid = threadIdx.x;
  const int w = tid >> 6, l = tid & 63;
  const int quad = l >> 4, lr = l & 15;
  const int wr = w >> 2, wc = w & 3;         // wave grid 2 (M) x 4 (N)
  const int m0 = mb * BM, n0 = nt * BN;

  // Staging: slot s = kb*256 + row (kb = K-chunk of 8 bf16). Thread tid
  // handles row = tid&255 at kb = j*2 + (tid>>8), j = 0..3 (4 x 16B per
  // matrix per K-tile; 512 threads cover all 2048 slots).
  const int srow = tid & 255, shi = tid >> 8;
  const unsigned short* gA = A + (size_t)(m0 + srow) * H_ + shi * 8;
  const unsigned short* gB = Bw + (size_t)(n0 + srow) * H_ + shi * 8;
  const int ldsoff = (shi * 256 + srow) * 16;

  f32x4 acc[8][4] = {};

  // Fragment read bases: A row = wr*128 + i*16 + lr, kb = kk*4 + quad.
  const int abOff = quad * 4096 + (wr * 128 + lr) * 16;
  const int bbOff = ABYTES + quad * 4096 + (wc * 64 + lr) * 16;

  auto stage = [&](int p, int kt) {
    const unsigned short* a = gA + kt * BK;
    const unsigned short* b = gB + kt * BK;
    char* la = smem + p * BUFBYTES + ldsoff;
    char* lb = la + ABYTES;
#pragma unroll
    for (int j = 0; j < 4; ++j) {
      async_copy16(a + j * 16, la + j * 8192);   // kb = 2j + shi
      async_copy16(b + j * 16, lb + j * 8192);
    }
  };

  auto compute = [&](int p) {
    const char* ab = smem + p * BUFBYTES + abOff;
    const char* bb = smem + p * BUFBYTES + bbOff;
#pragma unroll
    for (int kk = 0; kk < 2; ++kk) {
      short8 af[8], bf[4];
#pragma unroll
      for (int i = 0; i < 8; ++i)
        af[i] = *(const short8*)(ab + kk * 16384 + i * 256);
#pragma unroll
      for (int j = 0; j < 4; ++j)
        bf[j] = *(const short8*)(bb + kk * 16384 + j * 256);
      __builtin_amdgcn_s_setprio(1);
#pragma unroll
      for (int i = 0; i < 8; ++i)
#pragma unroll
        for (int j = 0; j < 4; ++j)
          acc[i][j] = __builtin_amdgcn_mfma_f32_16x16x32_bf16(
              af[i], bf[j], acc[i][j], 0, 0, 0);
      __builtin_amdgcn_s_setprio(0);
    }
  };

  // Prologue: stage tile 0, wait, go.
  stage(0, 0);
  __syncthreads();
  int p = 0;
  for (int kt = 1; kt < NKT; ++kt) {
    stage(p ^ 1, kt);     // issue next tile's loads FIRST (latency hiding)
    compute(p);           // full K-tile of MFMA under the loads
    __syncthreads();      // drains vmcnt(0): next tile ready, buf p free
    p ^= 1;
  }
  compute(p);             // epilogue tile (no prefetch)

  // Epilogue: C/D layout col = lane&15 (n), row = quad*4 + reg.
  // Per-wave slab = 64 cols -> same partial definition as before (NP = 500).
  const int p_idx = nt * 4 + wc;
#pragma unroll
  for (int i = 0; i < 8; ++i) {
#pragma unroll
    for (int r = 0; r < 4; ++r) {
      float vmax = fmaxf(fmaxf(acc[i][0][r], acc[i][1][r]),
                         fmaxf(acc[i][2][r], acc[i][3][r]));
#pragma unroll
      for (int off = 8; off; off >>= 1) vmax = fmaxf(vmax, __shfl_xor(vmax, off, 64));
      float s = __expf(acc[i][0][r] - vmax) + __expf(acc[i][1][r] - vmax) +
                __expf(acc[i][2][r] - vmax) + __expf(acc[i][3][r] - vmax);
#pragma unroll
      for (int off = 8; off; off >>= 1) s += __shfl_xor(s, off, 64);
      if (lr == 0) {
        int mg = m0 + wr * 128 + i * 16 + quad * 4 + r;
        pmax[(size_t)mg * NPAD + p_idx] = vmax;
        psum[(size_t)mg * NPAD + p_idx] = s;
      }
    }
  }
}

// One wave per (model, token): coalesced read of the token's 500 partials,
// online-merge per lane, shuffle-combine across lanes, write logp.
__global__ void lse_merge_kernel(
    const float* __restrict__ pmaxP, const float* __restrict__ psumP,
    const float* __restrict__ pmaxR, const float* __restrict__ psumR,
    const float* __restrict__ sel, float* __restrict__ lp) {
  int gw = (blockIdx.x * 256 + threadIdx.x) >> 6;  // 0..4095
  int l = threadIdx.x & 63;
  int md = gw >> 11, m = gw & (M_ - 1);
  const float* pm = (md ? pmaxR : pmaxP) + (size_t)m * NPAD;
  const float* ps = (md ? psumR : psumP) + (size_t)m * NPAD;
  float mx = -3.0e38f, s = 0.0f;
  for (int p = l; p < NP; p += 64) {
    float a = pm[p], b = ps[p];
    float nm = fmaxf(mx, a);
    s = s * __expf(mx - nm) + b * __expf(a - nm);
    mx = nm;
  }
#pragma unroll
  for (int off = 32; off; off >>= 1) {
    float omx = __shfl_xor(mx, off, 64);
    float os  = __shfl_xor(s, off, 64);
    float nm = fmaxf(mx, omx);
    s = s * __expf(mx - nm) + os * __expf(omx - nm);
    mx = nm;
  }
  if (l == 0) lp[md * M_ + m] = sel[md * M_ + m] - (mx + __logf(s));
}

// Single block: GRPO loss terms + masked mean. coef1=coef2=1 exactly
// (old_logps == stop_gradient(logps)), so loss = mean(-adv + BETA*kl).
__global__ void loss_kernel(const float* __restrict__ lp,
                            const float* __restrict__ adv,
                            const int* __restrict__ mask,
                            float* __restrict__ out) {
  __shared__ float sp[16], sm[16];
  int t = threadIdx.x;
  float pt = 0.0f, mk = 0.0f;
  for (int m = t; m < M_; m += 1024) {
    float d = lp[M_ + m] - lp[m];       // ref_logp - logp
    float kl = __expf(d) - d - 1.0f;
    float mkm = (float)mask[m];
    pt += (-adv[m >> 9] + BETA_ * kl) * mkm;
    mk += mkm;
  }
#pragma unroll
  for (int off = 32; off; off >>= 1) {
    pt += __shfl_xor(pt, off, 64);
    mk += __shfl_xor(mk, off, 64);
  }
  int wv = t >> 6, l = t & 63;
  if (l == 0) { sp[wv] = pt; sm[wv] = mk; }
  __syncthreads();
  if (t == 0) {
    float a = 0.0f, b = 0.0f;
#pragma unroll
    for (int i = 0; i < 16; ++i) { a += sp[i]; b += sm[i]; }
    out[0] = a / fmaxf(b, 1.0f);
  }
}

extern "C" void kernel_launch(void* const* d_in, const int* in_sizes, int n_in,
                              void* d_out, int out_size, void* d_ws, size_t ws_size,
                              hipStream_t stream) {
  const float* x    = (const float*)d_in[0];
  const float* lw   = (const float*)d_in[1];
  const float* rx   = (const float*)d_in[2];
  const float* rw   = (const float*)d_in[3];
  const float* adv  = (const float*)d_in[4];
  const int*   ids  = (const int*)d_in[5];
  const int*   mask = (const int*)d_in[6];
  float* out = (float*)d_out;

  // 128 KB dynamic LDS needs the attribute bump (host-side, not captured).
  static bool s_attr_set = false;
  if (!s_attr_set) {
    hipFuncSetAttribute(reinterpret_cast<const void*>(gemm_lse_kernel),
                        hipFuncAttributeMaxDynamicSharedMemorySize, LDS_TOTAL);
    s_attr_set = true;
  }

  // Workspace: Wb (bf16) | xb (bf16) | pmaxP|psumP|pmaxR|psumR ([M_][NPAD] f32)
  // | sel [2][M_] | lp [2][M_]   (~156.3 MB)
  char* ws = (char*)d_ws;
  unsigned short* Wb = (unsigned short*)ws;
  unsigned short* xb = (unsigned short*)(ws + (size_t)V_ * H_ * 2);
  char* p0 = ws + (size_t)V_ * H_ * 2 + (size_t)M_ * H_ * 2;
  const size_t PSZ = (size_t)M_ * NPAD * 4;
  float* pmaxP = (float*)(p0);
  float* psumP = (float*)(p0 + 1 * PSZ);
  float* pmaxR = (float*)(p0 + 2 * PSZ);
  float* psumR = (float*)(p0 + 3 * PSZ);
  float* sel   = (float*)(p0 + 4 * PSZ);
  float* lp    = (float*)(p0 + 4 * PSZ + 2 * M_ * 4);

  const int n4x = M_ * H_ / 4, n4w = V_ * H_ / 4;

  // Policy model
  cvt_bf16_kernel<<<(n4x + 255) / 256, 256, 0, stream>>>(x, xb, n4x);
  cvt_bf16_kernel<<<(n4w + 255) / 256, 256, 0, stream>>>(lw, Wb, n4w);
  sel_kernel<<<(2 * M_) / 4, 256, 0, stream>>>(x, lw, rx, rw, ids, sel);
  gemm_lse_kernel<<<GRID_GEMM, 512, LDS_TOTAL, stream>>>(xb, Wb, pmaxP, psumP);
  // Ref model (reuse bf16 buffers — stream-ordered)
  cvt_bf16_kernel<<<(n4x + 255) / 256, 256, 0, stream>>>(rx, xb, n4x);
  cvt_bf16_kernel<<<(n4w + 255) / 256, 256, 0, stream>>>(rw, Wb, n4w);
  gemm_lse_kernel<<<GRID_GEMM, 512, LDS_TOTAL, stream>>>(xb, Wb, pmaxR, psumR);

  lse_merge_kernel<<<(2 * M_) / 4, 256, 0, stream>>>(pmaxP, psumP, pmaxR, psumR,
                                                     sel, lp);
  loss_kernel<<<1, 1024, 0, stream>>>(lp, adv, mask, out);
}

// Round 2
// 1430.739 us; speedup vs baseline: 1.1802x; 1.1802x over previous
//
#include <hip/hip_runtime.h>
#include <hip/hip_bf16.h>

// Problem constants (from reference): B=4, T=512, H=2048, V=32000
#define B_ 4
#define T_ 512
#define H_ 2048
#define V_ 32000
#define M_ (B_ * T_)          // 2048 tokens
#define BETA_ 0.1f

// GEMM tiling: 256x256 block tile, BK=32, 512 threads = 8 waves (2M x 4N),
// each wave owns a 128x64 output sub-tile. LDS: THREE 32 KB K-tile buffers,
// depth-2 software pipeline with counted vmcnt (T4) — never drains to 0 in
// the main loop, and no __syncthreads() (whose implicit vmcnt(0) drain was
// the round-1 bottleneck: MfmaUtil pinned at 19% while HBM sat at 4.7%).
#define BM 256
#define BN 256
#define BK 32
#define NKT (H_ / BK)         // 64 k-tiles
#define NTILES (V_ / BN)      // 125 n-tiles
#define NP (NTILES * 4)       // 500 partial slabs (64 cols each) per row
#define NPAD 512              // padded row length for [m][p] partial layout
#define GRID_GEMM 1024        // 8 xcd * 128 g; g>>3 -> nt-group, g&7 -> mb

#define TILEB (BM * BK * 2)       // 16 KB per A (or B) K-tile slab
#define BUFB (2 * TILEB)          // 32 KB: A slab then B slab
#define NBUF 3
#define LDS_TOTAL (NBUF * BUFB)   // 96 KB

typedef __attribute__((ext_vector_type(8))) short short8;  // 8 bf16 = 4 VGPRs
typedef __attribute__((ext_vector_type(4))) float f32x4;   // MFMA accumulator

__device__ __forceinline__ void async_copy16(const void* g, void* l) {
  // global -> LDS direct copy, 16B per lane. LDS dest is wave-uniform
  // base + lane*16 (slot index is lane-linear within each wave).
  __builtin_amdgcn_global_load_lds(
      (const __attribute__((address_space(1))) void*)g,
      (__attribute__((address_space(3))) void*)l, 16, 0, 0);
}

// Hard barrier: raw s_barrier with compiler-motion fences. Deliberately does
// NOT drain vmcnt (that is the whole point — global_load_lds stay in flight).
__device__ __forceinline__ void hard_barrier() {
  asm volatile("" ::: "memory");
  __builtin_amdgcn_sched_barrier(0);
  __builtin_amdgcn_s_barrier();
  __builtin_amdgcn_sched_barrier(0);
  asm volatile("" ::: "memory");
}

__device__ __forceinline__ unsigned short f2bf(float f) {
  unsigned int u = __float_as_uint(f);
  u += 0x7fffu + ((u >> 16) & 1u);
  return (unsigned short)(u >> 16);
}

__global__ void cvt_bf16_kernel(const float* __restrict__ in,
                                unsigned short* __restrict__ out, int n4) {
  int i = blockIdx.x * blockDim.x + threadIdx.x;
  if (i < n4) {
    float4 v = ((const float4*)in)[i];
    ushort4 o;
    o.x = f2bf(v.x); o.y = f2bf(v.y); o.z = f2bf(v.z); o.w = f2bf(v.w);
    ((ushort4*)out)[i] = o;
  }
}

// Selected logit: exact fp32 dot(x[m,:], W[ids[m],:]). One wave per (model, token).
__global__ void sel_kernel(const float* __restrict__ x, const float* __restrict__ w,
                           const float* __restrict__ rx, const float* __restrict__ rw,
                           const int* __restrict__ ids, float* __restrict__ sel) {
  int gw = (blockIdx.x * 256 + threadIdx.x) >> 6;  // global wave id, 0..4095
  int l = threadIdx.x & 63;
  int md = gw >> 11;          // model: 0 = policy, 1 = ref
  int m = gw & (M_ - 1);      // token
  const float* xr = (md ? rx : x) + (size_t)m * H_;
  const float* wr = (md ? rw : w) + (size_t)ids[m] * H_;
  float s = 0.0f;
#pragma unroll
  for (int it = 0; it < H_ / 256; ++it) {
    int k = it * 256 + l * 4;
    float4 a = *(const float4*)(xr + k);
    float4 b = *(const float4*)(wr + k);
    s += a.x * b.x + a.y * b.y + a.z * b.z + a.w * b.w;
  }
#pragma unroll
  for (int off = 32; off; off >>= 1) s += __shfl_xor(s, off, 64);
  if (l == 0) sel[md * M_ + m] = s;
}

// Fused bf16 MFMA GEMM (logits = A * Bw^T) + per-row online (max, sumexp) over
// each wave's 64-column slab.
//
// Pipeline (T4 counted-vmcnt, depth 2, 3 buffers):
//   prologue: stage(K0), stage(K1)
//   iter t:   stage(K[t+2]) -> s_waitcnt vmcnt(8)  [t+1,t+2 stay in flight;
//             per-wave guarantee that t's 4 loads landed]
//             -> s_barrier  [ALL waves' t-loads landed]
//             -> compute(t) [12 ds_read_b128 + 32 MFMA per wave]
//             -> s_barrier  [buf[t%3] reads done before t+3 overwrites it]
//   tail:     vmcnt(4) / vmcnt(0) peeled iterations.
// Race proof: stage(t+2) writes buf[(t+2)%3] == buf[(t-1)%3], whose last
// readers (compute(t-1)) passed the trailing barrier of iter t-1. Issue->need
// distance for a load = 2 iterations (~2500 cyc MFMA) > 900-cyc HBM miss.
//
// LDS layout per tile: K-outer [kb 0..3][row 0..255][16B] — lane-linear rows
// make staging legal for global_load_lds and ds_read_b128 fragment reads
// conflict-free (SQ_LDS_BANK_CONFLICT == 0 measured).
//
// XCD-aware decode: the 8 m-blocks of one n-tile land consecutively on one
// XCD (linear&7) so the B k-slices are fetched into that XCD's L2 once.
__global__ __launch_bounds__(512, 2) void gemm_lse_kernel(
    const unsigned short* __restrict__ A,    // [M_][H_] bf16
    const unsigned short* __restrict__ Bw,   // [V_][H_] bf16
    float* __restrict__ pmax,                // [M_][NPAD]
    float* __restrict__ psum) {              // [M_][NPAD]
  const int linear = blockIdx.x;
  const int c = linear & 7, g = linear >> 3;
  const int nt = (g >> 3) * 8 + c;           // n-tile, xcd-grouped
  if (nt >= NTILES) return;
  const int mb = g & 7;                      // m-block

  extern __shared__ char smem[];             // 3 x (A 16KB | B 16KB)

  const int tid = threadIdx.x;
  const int w = tid >> 6, l = tid & 63;
  const int quad = l >> 4, lr = l & 15;
  const int wr = w >> 2, wc = w & 3;         // wave grid 2 (M) x 4 (N)
  const int m0 = mb * BM, n0 = nt * BN;

  // Staging: slot s = kb*256 + row, 16 B each. Thread tid handles slots
  // {tid, tid+512} of A and of B: row = tid&255, kb = (tid>>8) and (tid>>8)+2.
  // 4 global_load_lds per thread per K-tile.
  const int srow = tid & 255, shi = tid >> 8;
  const unsigned short* gA = A + (size_t)(m0 + srow) * H_ + shi * 8;
  const unsigned short* gB = Bw + (size_t)(n0 + srow) * H_ + shi * 8;

  f32x4 acc[8][4] = {};

  // Fragment read bases (within a buffer): A row = wr*128 + i*16 + lr at
  // kb = quad; B row = wc*64 + j*16 + lr at kb = quad.
  const int abOff = quad * 4096 + (wr * 128 + lr) * 16;
  const int bbOff = TILEB + quad * 4096 + (wc * 64 + lr) * 16;

  auto stage = [&](int b, int kt) {
    const unsigned short* a = gA + kt * BK;
    const unsigned short* bsrc = gB + kt * BK;
    char* la = smem + b * BUFB + tid * 16;
    char* lb = la + TILEB;
    async_copy16(a, la);                 // kb = shi
    async_copy16(a + 16, la + 8192);     // kb = shi + 2
    async_copy16(bsrc, lb);
    async_copy16(bsrc + 16, lb + 8192);
  };

  auto compute = [&](int b) {
    const char* ab = smem + b * BUFB + abOff;
    const char* bb = smem + b * BUFB + bbOff;
    short8 af[8], bf[4];
#pragma unroll
    for (int i = 0; i < 8; ++i) af[i] = *(const short8*)(ab + i * 256);
#pragma unroll
    for (int j = 0; j < 4; ++j) bf[j] = *(const short8*)(bb + j * 256);
    __builtin_amdgcn_s_setprio(1);
#pragma unroll
    for (int i = 0; i < 8; ++i)
#pragma unroll
      for (int j = 0; j < 4; ++j)
        acc[i][j] = __builtin_amdgcn_mfma_f32_16x16x32_bf16(
            af[i], bf[j], acc[i][j], 0, 0, 0);
    __builtin_amdgcn_s_setprio(0);
  };

  // Prologue: two K-tiles in flight before any wait.
  stage(0, 0);
  stage(1, 1);
  for (int t = 0; t < NKT - 2; ++t) {
    stage((t + 2) % NBUF, t + 2);
    asm volatile("s_waitcnt vmcnt(8)" ::: "memory");   // t's loads landed
    hard_barrier();                                     // ...for ALL waves
    compute(t % NBUF);
    hard_barrier();                                     // buf free for t+3
  }
  // t = NKT-2: only K[NKT-1]'s 4 loads may remain in flight.
  asm volatile("s_waitcnt vmcnt(4)" ::: "memory");
  hard_barrier();
  compute((NKT - 2) % NBUF);
  hard_barrier();
  // t = NKT-1: drain.
  asm volatile("s_waitcnt vmcnt(0)" ::: "memory");
  hard_barrier();
  compute((NKT - 1) % NBUF);

  // Epilogue: C/D layout col = lane&15 (n), row = quad*4 + reg.
  // Per-wave slab = 64 cols -> partial definition unchanged (NP = 500).
  const int p_idx = nt * 4 + wc;
#pragma unroll
  for (int i = 0; i < 8; ++i) {
#pragma unroll
    for (int r = 0; r < 4; ++r) {
      float vmax = fmaxf(fmaxf(acc[i][0][r], acc[i][1][r]),
                         fmaxf(acc[i][2][r], acc[i][3][r]));
#pragma unroll
      for (int off = 8; off; off >>= 1) vmax = fmaxf(vmax, __shfl_xor(vmax, off, 64));
      float s = __expf(acc[i][0][r] - vmax) + __expf(acc[i][1][r] - vmax) +
                __expf(acc[i][2][r] - vmax) + __expf(acc[i][3][r] - vmax);
#pragma unroll
      for (int off = 8; off; off >>= 1) s += __shfl_xor(s, off, 64);
      if (lr == 0) {
        int mg = m0 + wr * 128 + i * 16 + quad * 4 + r;
        pmax[(size_t)mg * NPAD + p_idx] = vmax;
        psum[(size_t)mg * NPAD + p_idx] = s;
      }
    }
  }
}

// One wave per (model, token): coalesced read of the token's 500 partials,
// online-merge per lane, shuffle-combine across lanes, write logp.
__global__ void lse_merge_kernel(
    const float* __restrict__ pmaxP, const float* __restrict__ psumP,
    const float* __restrict__ pmaxR, const float* __restrict__ psumR,
    const float* __restrict__ sel, float* __restrict__ lp) {
  int gw = (blockIdx.x * 256 + threadIdx.x) >> 6;  // 0..4095
  int l = threadIdx.x & 63;
  int md = gw >> 11, m = gw & (M_ - 1);
  const float* pm = (md ? pmaxR : pmaxP) + (size_t)m * NPAD;
  const float* ps = (md ? psumR : psumP) + (size_t)m * NPAD;
  float mx = -3.0e38f, s = 0.0f;
  for (int p = l; p < NP; p += 64) {
    float a = pm[p], b = ps[p];
    float nm = fmaxf(mx, a);
    s = s * __expf(mx - nm) + b * __expf(a - nm);
    mx = nm;
  }
#pragma unroll
  for (int off = 32; off; off >>= 1) {
    float omx = __shfl_xor(mx, off, 64);
    float os  = __shfl_xor(s, off, 64);
    float nm = fmaxf(mx, omx);
    s = s * __expf(mx - nm) + os * __expf(omx - nm);
    mx = nm;
  }
  if (l == 0) lp[md * M_ + m] = sel[md * M_ + m] - (mx + __logf(s));
}

// Single block: GRPO loss terms + masked mean. coef1=coef2=1 exactly
// (old_logps == stop_gradient(logps)), so loss = mean(-adv + BETA*kl).
__global__ void loss_kernel(const float* __restrict__ lp,
                            const float* __restrict__ adv,
                            const int* __restrict__ mask,
                            float* __restrict__ out) {
  __shared__ float sp[16], sm[16];
  int t = threadIdx.x;
  float pt = 0.0f, mk = 0.0f;
  for (int m = t; m < M_; m += 1024) {
    float d = lp[M_ + m] - lp[m];       // ref_logp - logp
    float kl = __expf(d) - d - 1.0f;
    float mkm = (float)mask[m];
    pt += (-adv[m >> 9] + BETA_ * kl) * mkm;
    mk += mkm;
  }
#pragma unroll
  for (int off = 32; off; off >>= 1) {
    pt += __shfl_xor(pt, off, 64);
    mk += __shfl_xor(mk, off, 64);
  }
  int wv = t >> 6, l = t & 63;
  if (l == 0) { sp[wv] = pt; sm[wv] = mk; }
  __syncthreads();
  if (t == 0) {
    float a = 0.0f, b = 0.0f;
#pragma unroll
    for (int i = 0; i < 16; ++i) { a += sp[i]; b += sm[i]; }
    out[0] = a / fmaxf(b, 1.0f);
  }
}

extern "C" void kernel_launch(void* const* d_in, const int* in_sizes, int n_in,
                              void* d_out, int out_size, void* d_ws, size_t ws_size,
                              hipStream_t stream) {
  const float* x    = (const float*)d_in[0];
  const float* lw   = (const float*)d_in[1];
  const float* rx   = (const float*)d_in[2];
  const float* rw   = (const float*)d_in[3];
  const float* adv  = (const float*)d_in[4];
  const int*   ids  = (const int*)d_in[5];
  const int*   mask = (const int*)d_in[6];
  float* out = (float*)d_out;

  // 96 KB dynamic LDS needs the attribute bump (host-side, not captured).
  static bool s_attr_set = false;
  if (!s_attr_set) {
    hipFuncSetAttribute(reinterpret_cast<const void*>(gemm_lse_kernel),
                        hipFuncAttributeMaxDynamicSharedMemorySize, LDS_TOTAL);
    s_attr_set = true;
  }

  // Workspace: Wb (bf16) | xb (bf16) | pmaxP|psumP|pmaxR|psumR ([M_][NPAD] f32)
  // | sel [2][M_] | lp [2][M_]   (~156.3 MB)
  char* ws = (char*)d_ws;
  unsigned short* Wb = (unsigned short*)ws;
  unsigned short* xb = (unsigned short*)(ws + (size_t)V_ * H_ * 2);
  char* p0 = ws + (size_t)V_ * H_ * 2 + (size_t)M_ * H_ * 2;
  const size_t PSZ = (size_t)M_ * NPAD * 4;
  float* pmaxP = (float*)(p0);
  float* psumP = (float*)(p0 + 1 * PSZ);
  float* pmaxR = (float*)(p0 + 2 * PSZ);
  float* psumR = (float*)(p0 + 3 * PSZ);
  float* sel   = (float*)(p0 + 4 * PSZ);
  float* lp    = (float*)(p0 + 4 * PSZ + 2 * M_ * 4);

  const int n4x = M_ * H_ / 4, n4w = V_ * H_ / 4;

  // Policy model
  cvt_bf16_kernel<<<(n4x + 255) / 256, 256, 0, stream>>>(x, xb, n4x);
  cvt_bf16_kernel<<<(n4w + 255) / 256, 256, 0, stream>>>(lw, Wb, n4w);
  sel_kernel<<<(2 * M_) / 4, 256, 0, stream>>>(x, lw, rx, rw, ids, sel);
  gemm_lse_kernel<<<GRID_GEMM, 512, LDS_TOTAL, stream>>>(xb, Wb, pmaxP, psumP);
  // Ref model (reuse bf16 buffers — stream-ordered)
  cvt_bf16_kernel<<<(n4x + 255) / 256, 256, 0, stream>>>(rx, xb, n4x);
  cvt_bf16_kernel<<<(n4w + 255) / 256, 256, 0, stream>>>(rw, Wb, n4w);
  gemm_lse_kernel<<<GRID_GEMM, 512, LDS_TOTAL, stream>>>(xb, Wb, pmaxR, psumR);

  lse_merge_kernel<<<(2 * M_) / 4, 256, 0, stream>>>(pmaxP, psumP, pmaxR, psumR,
                                                     sel, lp);
  loss_kernel<<<1, 1024, 0, stream>>>(lp, adv, mask, out);
}